// Round 10
// baseline (487.110 us; speedup 1.0000x reference)
//
#include <hip/hip_runtime.h>

#define T_N 1024
#define H_N 128
#define CH   64
#define NCH (T_N / CH)     // 16
#define WPAD 136           // shorts per row of bf16 weight tiles
#define PPAD 68            // floats per row of pT

typedef __attribute__((ext_vector_type(8))) short bf16x8;
typedef __attribute__((ext_vector_type(4))) float f32x4;

__device__ __forceinline__ short f2bf_rne(float f) {
    union { float f; unsigned int i; } v; v.f = f;
    unsigned int r = v.i + 0x7FFFu + ((v.i >> 16) & 1u);
    return (short)(r >> 16);
}

// TWO batch rows per block as TWO INDEPENDENT 8-WAVE GROUPS (1024 thr, 16
// waves, 4 waves/SIMD; grid 128). Round-8 showed the step is a ~585cy latency
// chain with the SIMD mostly idle; round-5 showed same-wave interleave fails
// (issue doubles). Here row B's waves fill row A's stall slots on the same
// SIMDs: per-wave step work unchanged (4 MFMA + 1 tanh), chains overlap in the
// wave dimension, shared __syncthreads couples two equal-length chains
// (benign). ~2x throughput at ~same step wall.
// Per group: round-8 structure verbatim (8-step sub-unroll, p-register-block,
// rcp-tanh, cvt_pk, static LDS addrs, uniform 64-step chunks, zero-state c0).
__global__ __launch_bounds__(1024, 1) void k_fused(const float* __restrict__ x,
                                                   const float* __restrict__ w,
                                                   const float* __restrict__ wst,
                                                   const float* __restrict__ bias,
                                                   float* __restrict__ out) {
    __shared__ __align__(16) short wT[H_N * WPAD];      // input-proj w, bf16 [n][k] (shared)
    __shared__ __align__(16) float pT[2][H_N * PPAD];   // per-group proj chunk; pT[0] = wsT staging at startup
    __shared__ __align__(16) short sst[2][2][H_N];      // per-group state double buffer, bf16

    const int tid  = threadIdx.x;
    const int grp  = tid >> 9;       // 0,1: row group (waves 0-7 / 8-15)
    const int wg   = (tid >> 6) & 7; // wave within group: step cols 16wg..+15
    const int lane = tid & 63;
    const int l = lane & 15;
    const int q = lane >> 4;
    const int tt = wg >> 1;          // GEMM t-tile (x rows 16tt..+15)
    const int h  = wg & 1;           // GEMM nt half: nt in {4h..4h+3}
    const int r = blockIdx.x * 2 + grp;
    const float* xrow = x + (size_t)r * T_N * H_N;
    float* pTg = pT[grp];
    const f32x4 zero4 = (f32x4){0.f, 0.f, 0.f, 0.f};

    // ---- VGPR staging: chunk 0's x rows for this lane (32 VGPRs) ----
    const float* xlane = xrow + (size_t)(tt * 16 + l) * H_N + q * 8;
    float4 xst[8];   // [ks][half]: x[16tt+l][32ks+8q .. +7]
    #pragma unroll
    for (int ks = 0; ks < 4; ++ks) {
        xst[ks * 2 + 0] = *reinterpret_cast<const float4*>(xlane + ks * 32);
        xst[ks * 2 + 1] = *reinterpret_cast<const float4*>(xlane + ks * 32 + 4);
    }

    // ---- stage wst (bf16 [n][k]) through pT[0]'s memory (all 1024 threads) ----
    short* wsTs = reinterpret_cast<short*>(&pT[0][0]);
    for (int e = tid * 4; e < H_N * H_N; e += 4096) {
        int k = e >> 7, n = e & 127;
        float4 a4 = *reinterpret_cast<const float4*>(wst + e);
        wsTs[(n + 0) * WPAD + k] = f2bf_rne(a4.x);
        wsTs[(n + 1) * WPAD + k] = f2bf_rne(a4.y);
        wsTs[(n + 2) * WPAD + k] = f2bf_rne(a4.z);
        wsTs[(n + 3) * WPAD + k] = f2bf_rne(a4.w);
    }
    __syncthreads();

    bf16x8 wf[4];   // state-W B-frags for this wave's single nt = wg (same for both groups)
    #pragma unroll
    for (int ks = 0; ks < 4; ++ks)
        wf[ks] = *reinterpret_cast<const bf16x8*>(
            &wsTs[(16 * wg + l) * WPAD + ks * 32 + q * 8]);

    // zero state (bf16 +0.0): step 0 then computes tanh(p0 + W*0) = state0
    {
        int gt = tid & 511;
        if (gt < 128) sst[grp][0][gt] = 0;
    }

    // ---- input-proj weights -> bf16 [n][k] LDS (all 1024 threads) ----
    for (int e = tid * 4; e < H_N * H_N; e += 4096) {
        int k = e >> 7, n = e & 127;
        float4 a4 = *reinterpret_cast<const float4*>(w + e);
        wT[(n + 0) * WPAD + k] = f2bf_rne(a4.x);
        wT[(n + 1) * WPAD + k] = f2bf_rne(a4.y);
        wT[(n + 2) * WPAD + k] = f2bf_rne(a4.z);
        wT[(n + 3) * WPAD + k] = f2bf_rne(a4.w);
    }

    float bv[4];
    #pragma unroll
    for (int j = 0; j < 4; ++j) bv[j] = bias[(4 * h + j) * 16 + l];

    __syncthreads();   // wf gathered (both groups), sst zeroed, wT staged -> pT[0] reusable

    float y = 0.f;
    const int rowp = (16 * wg + l) * PPAD;

    // one recurrence step: read srd state, matvec (+pv via C), tanh, write swr
    auto step = [&](const short* srd, short* swr, float pv) {
        bf16x8 a0 = *reinterpret_cast<const bf16x8*>(&srd[ 0 + q * 8]);
        bf16x8 a1 = *reinterpret_cast<const bf16x8*>(&srd[32 + q * 8]);
        bf16x8 a2 = *reinterpret_cast<const bf16x8*>(&srd[64 + q * 8]);
        bf16x8 a3 = *reinterpret_cast<const bf16x8*>(&srd[96 + q * 8]);
        f32x4 c4 = (f32x4){pv, pv, pv, pv};   // pv known 8 steps early: movs off-chain
        f32x4 x0 = __builtin_amdgcn_mfma_f32_16x16x32_bf16(a0, wf[0], c4, 0, 0, 0);
        f32x4 x1 = __builtin_amdgcn_mfma_f32_16x16x32_bf16(a1, wf[1], zero4, 0, 0, 0);
        f32x4 x2 = __builtin_amdgcn_mfma_f32_16x16x32_bf16(a2, wf[2], zero4, 0, 0, 0);
        f32x4 x3 = __builtin_amdgcn_mfma_f32_16x16x32_bf16(a3, wf[3], zero4, 0, 0, 0);
        float z = (x0[0] + x1[0]) + (x2[0] + x3[0]);   // includes pv via C-init
        float e = __expf(2.0f * z);
        y = __builtin_fmaf(-2.0f, __builtin_amdgcn_rcpf(e + 1.0f), 1.0f);
        unsigned int pk;
        asm("v_cvt_pk_bf16_f32 %0, %1, %2" : "=v"(pk) : "v"(y), "v"(y));
        if (q == 0)
            swr[16 * wg + l] = (short)pk;
        __syncthreads();   // y_t visible to all waves (both groups in lockstep)
    };

    #pragma unroll 1
    for (int c = 0; c < NCH; ++c) {
        // ---- cvt staged x -> bf16 A-frags (the only vmcnt wait) ----
        bf16x8 ax[4];
        #pragma unroll
        for (int ks = 0; ks < 4; ++ks) {
            float4 u0 = xst[ks * 2 + 0];
            float4 u1 = xst[ks * 2 + 1];
            bf16x8 f;
            f[0] = f2bf_rne(u0.x); f[1] = f2bf_rne(u0.y);
            f[2] = f2bf_rne(u0.z); f[3] = f2bf_rne(u0.w);
            f[4] = f2bf_rne(u1.x); f[5] = f2bf_rne(u1.y);
            f[6] = f2bf_rne(u1.z); f[7] = f2bf_rne(u1.w);
            ax[ks] = f;
        }

        // ---- issue chunk c+1's staging loads (in flight across the step loop) ----
        if (c + 1 < NCH) {
            const float* pn = xlane + (size_t)(c + 1) * CH * H_N;
            #pragma unroll
            for (int ks = 0; ks < 4; ++ks) {
                xst[ks * 2 + 0] = *reinterpret_cast<const float4*>(pn + ks * 32);
                xst[ks * 2 + 1] = *reinterpret_cast<const float4*>(pn + ks * 32 + 4);
            }
        }

        // NOTE: no barrier here — the previous chunk's final step barrier
        // already ordered all pT reads before these writes (both groups).

        // ---- chunk GEMM: wave (tt,h) -> own group's proj rows, nt 4h..4h+3 ----
        #pragma unroll
        for (int j = 0; j < 4; ++j) {
            const int nt = 4 * h + j;
            f32x4 cb = (f32x4){bv[j], bv[j], bv[j], bv[j]};
            f32x4 acc;
            #pragma unroll
            for (int ks = 0; ks < 4; ++ks) {
                bf16x8 bw = *reinterpret_cast<const bf16x8*>(
                    &wT[(nt * 16 + l) * WPAD + ks * 32 + q * 8]);
                acc = __builtin_amdgcn_mfma_f32_16x16x32_bf16(
                    ax[ks], bw, ks == 0 ? cb : acc, 0, 0, 0);
            }
            *reinterpret_cast<f32x4*>(&pTg[(nt * 16 + l) * PPAD + tt * 16 + q * 4]) = acc;
        }

        __syncthreads();   // both groups' pT ready

        // ---- step loop: 8 sub-blocks x 8 steps; p-block in regs, static idx ----
        short* s0 = sst[grp][0];
        short* s1 = sst[grp][1];
        #pragma unroll 1
        for (int s = 0; s < CH / 8; ++s) {
            float4 pb0 = *reinterpret_cast<const float4*>(&pTg[rowp + 8 * s]);
            float4 pb1 = *reinterpret_cast<const float4*>(&pTg[rowp + 8 * s + 4]);
            step(s0, s1, pb0.x);
            step(s1, s0, pb0.y);
            step(s0, s1, pb0.z);
            step(s1, s0, pb0.w);
            step(s0, s1, pb1.x);
            step(s1, s0, pb1.y);
            step(s0, s1, pb1.z);
            step(s1, s0, pb1.w);
        }
    }

    if (q == 0)
        out[r * H_N + 16 * wg + l] = y;
}

extern "C" void kernel_launch(void* const* d_in, const int* in_sizes, int n_in,
                              void* d_out, int out_size, void* d_ws, size_t ws_size,
                              hipStream_t stream) {
    const float* x    = (const float*)d_in[0];  // [B][T][D] fp32
    const float* w    = (const float*)d_in[1];  // [D][H]    fp32
    const float* wst  = (const float*)d_in[2];  // [H][H]    fp32
    const float* bias = (const float*)d_in[3];  // [H]       fp32
    float* out = (float*)d_out;                 // [B][H]    fp32

    k_fused<<<128, 1024, 0, stream>>>(x, w, wst, bias, out);
}

// Round 11
// 373.974 us; speedup vs baseline: 1.3025x; 1.3025x over previous
//
#include <hip/hip_runtime.h>

#define T_N 1024
#define H_N 128
#define CH   64
#define NCH (T_N / CH)     // 16
#define WPAD 136           // shorts per row of bf16 weight tiles
#define PPAD 68            // floats per row of pT

typedef __attribute__((ext_vector_type(8))) short bf16x8;
typedef __attribute__((ext_vector_type(4))) float f32x4;

__device__ __forceinline__ short f2bf_rne(float f) {
    union { float f; unsigned int i; } v; v.f = f;
    unsigned int r = v.i + 0x7FFFu + ((v.i >> 16) & 1u);
    return (short)(r >> 16);
}

// BEST MEASURED (round 8: 249.2us rocprof). One block per batch row, 8 waves.
// The kernel is a serial latency chain: 1023 steps x ~585cy (barrier + LDS
// state broadcast + depth-1 MFMA + rcp-tanh). Structural alternatives all
// measured worse: 1-wave no-barrier (rounds 1-4: >=1200cy/step), same-wave
// 2-row interleave (round 5), 16-wave 2-row co-location (rounds 9-10: per-CU
// 1.38x efficient but idles half the CUs since B == #CUs).
//  - 8-step sub-unroll + p-register-block (2x ds_read_b128 per 8 steps)
//  - rcp-tanh (no IEEE div), single cvt_pk for state, static LDS addrs
//  - uniform 64-step chunks from zero state; no chunk-top barrier
//  - x staged in VGPRs; next chunk's loads in flight across the step loop
__global__ __launch_bounds__(512, 1) void k_fused(const float* __restrict__ x,
                                                  const float* __restrict__ w,
                                                  const float* __restrict__ wst,
                                                  const float* __restrict__ bias,
                                                  float* __restrict__ out) {
    __shared__ __align__(16) short wT[H_N * WPAD];   // input-proj w, bf16 [n][k]
    __shared__ __align__(16) float pT[H_N * PPAD];   // proj chunk [h][t]; wsT staging at startup
    __shared__ __align__(16) short sst[2][H_N];      // state double buffer, bf16

    const int tid  = threadIdx.x;
    const int wv   = tid >> 6;       // 0..7: step cols 16wv..+15
    const int lane = tid & 63;
    const int l = lane & 15;
    const int q = lane >> 4;
    const int tt = wv >> 1;          // GEMM t-tile (x rows 16tt..+15)
    const int h  = wv & 1;           // GEMM nt half: nt in {4h..4h+3}
    const int r = blockIdx.x;
    const float* xrow = x + (size_t)r * T_N * H_N;
    const f32x4 zero4 = (f32x4){0.f, 0.f, 0.f, 0.f};

    // ---- VGPR staging: chunk 0's x rows for this lane (32 VGPRs) ----
    const float* xlane = xrow + (size_t)(tt * 16 + l) * H_N + q * 8;
    float4 xst[8];   // [ks][half]: x[16tt+l][32ks+8q .. +7]
    #pragma unroll
    for (int ks = 0; ks < 4; ++ks) {
        xst[ks * 2 + 0] = *reinterpret_cast<const float4*>(xlane + ks * 32);
        xst[ks * 2 + 1] = *reinterpret_cast<const float4*>(xlane + ks * 32 + 4);
    }

    // ---- stage wst (bf16 [n][k]) through pT's memory ----
    short* wsTs = reinterpret_cast<short*>(pT);
    for (int e = tid * 4; e < H_N * H_N; e += 2048) {
        int k = e >> 7, n = e & 127;
        float4 a4 = *reinterpret_cast<const float4*>(wst + e);
        wsTs[(n + 0) * WPAD + k] = f2bf_rne(a4.x);
        wsTs[(n + 1) * WPAD + k] = f2bf_rne(a4.y);
        wsTs[(n + 2) * WPAD + k] = f2bf_rne(a4.z);
        wsTs[(n + 3) * WPAD + k] = f2bf_rne(a4.w);
    }
    __syncthreads();

    bf16x8 wf[4];   // state-W B-frags for this wave's single nt = wv
    #pragma unroll
    for (int ks = 0; ks < 4; ++ks)
        wf[ks] = *reinterpret_cast<const bf16x8*>(
            &wsTs[(16 * wv + l) * WPAD + ks * 32 + q * 8]);

    // zero state (bf16 +0.0): step 0 then computes tanh(p0 + W*0) = state0
    if (tid < 128) sst[0][tid] = 0;

    // ---- input-proj weights -> bf16 [n][k] LDS ----
    for (int e = tid * 4; e < H_N * H_N; e += 2048) {
        int k = e >> 7, n = e & 127;
        float4 a4 = *reinterpret_cast<const float4*>(w + e);
        wT[(n + 0) * WPAD + k] = f2bf_rne(a4.x);
        wT[(n + 1) * WPAD + k] = f2bf_rne(a4.y);
        wT[(n + 2) * WPAD + k] = f2bf_rne(a4.z);
        wT[(n + 3) * WPAD + k] = f2bf_rne(a4.w);
    }

    float bv[4];
    #pragma unroll
    for (int j = 0; j < 4; ++j) bv[j] = bias[(4 * h + j) * 16 + l];

    __syncthreads();   // wf gathered, sst zeroed, wT staged -> safe to overwrite pT

    float y = 0.f;
    const int rowp = (16 * wv + l) * PPAD;

    // one recurrence step: read srd state, matvec (+pv via C), tanh, write swr
    auto step = [&](const short* srd, short* swr, float pv) {
        bf16x8 a0 = *reinterpret_cast<const bf16x8*>(&srd[ 0 + q * 8]);
        bf16x8 a1 = *reinterpret_cast<const bf16x8*>(&srd[32 + q * 8]);
        bf16x8 a2 = *reinterpret_cast<const bf16x8*>(&srd[64 + q * 8]);
        bf16x8 a3 = *reinterpret_cast<const bf16x8*>(&srd[96 + q * 8]);
        f32x4 c4 = (f32x4){pv, pv, pv, pv};   // pv known 8 steps early: movs off-chain
        f32x4 x0 = __builtin_amdgcn_mfma_f32_16x16x32_bf16(a0, wf[0], c4, 0, 0, 0);
        f32x4 x1 = __builtin_amdgcn_mfma_f32_16x16x32_bf16(a1, wf[1], zero4, 0, 0, 0);
        f32x4 x2 = __builtin_amdgcn_mfma_f32_16x16x32_bf16(a2, wf[2], zero4, 0, 0, 0);
        f32x4 x3 = __builtin_amdgcn_mfma_f32_16x16x32_bf16(a3, wf[3], zero4, 0, 0, 0);
        float z = (x0[0] + x1[0]) + (x2[0] + x3[0]);   // includes pv via C-init
        float e = __expf(2.0f * z);
        y = __builtin_fmaf(-2.0f, __builtin_amdgcn_rcpf(e + 1.0f), 1.0f);
        unsigned int pk;
        asm("v_cvt_pk_bf16_f32 %0, %1, %2" : "=v"(pk) : "v"(y), "v"(y));
        if (q == 0)
            swr[16 * wv + l] = (short)pk;
        __syncthreads();   // y_t visible to all waves (lgkm-only drain)
    };

    #pragma unroll 1
    for (int c = 0; c < NCH; ++c) {
        // ---- cvt staged x -> bf16 A-frags (the only vmcnt wait) ----
        bf16x8 ax[4];
        #pragma unroll
        for (int ks = 0; ks < 4; ++ks) {
            float4 u0 = xst[ks * 2 + 0];
            float4 u1 = xst[ks * 2 + 1];
            bf16x8 f;
            f[0] = f2bf_rne(u0.x); f[1] = f2bf_rne(u0.y);
            f[2] = f2bf_rne(u0.z); f[3] = f2bf_rne(u0.w);
            f[4] = f2bf_rne(u1.x); f[5] = f2bf_rne(u1.y);
            f[6] = f2bf_rne(u1.z); f[7] = f2bf_rne(u1.w);
            ax[ks] = f;
        }

        // ---- issue chunk c+1's staging loads (in flight across the step loop) ----
        if (c + 1 < NCH) {
            const float* pn = xlane + (size_t)(c + 1) * CH * H_N;
            #pragma unroll
            for (int ks = 0; ks < 4; ++ks) {
                xst[ks * 2 + 0] = *reinterpret_cast<const float4*>(pn + ks * 32);
                xst[ks * 2 + 1] = *reinterpret_cast<const float4*>(pn + ks * 32 + 4);
            }
        }

        // NOTE: no barrier here — the previous chunk's final step barrier
        // already ordered all pT reads before these writes.

        // ---- chunk GEMM: wave (tt,h) -> proj rows [c*64+16tt .. +15], nt 4h..4h+3 ----
        #pragma unroll
        for (int j = 0; j < 4; ++j) {
            const int nt = 4 * h + j;
            f32x4 cb = (f32x4){bv[j], bv[j], bv[j], bv[j]};
            f32x4 acc;
            #pragma unroll
            for (int ks = 0; ks < 4; ++ks) {
                bf16x8 bw = *reinterpret_cast<const bf16x8*>(
                    &wT[(nt * 16 + l) * WPAD + ks * 32 + q * 8]);
                acc = __builtin_amdgcn_mfma_f32_16x16x32_bf16(
                    ax[ks], bw, ks == 0 ? cb : acc, 0, 0, 0);
            }
            *reinterpret_cast<f32x4*>(&pT[(nt * 16 + l) * PPAD + tt * 16 + q * 4]) = acc;
        }

        __syncthreads();   // pT ready

        // ---- step loop: 8 sub-blocks x 8 steps; p-block in regs, static idx ----
        #pragma unroll 1
        for (int s = 0; s < CH / 8; ++s) {
            float4 pb0 = *reinterpret_cast<const float4*>(&pT[rowp + 8 * s]);
            float4 pb1 = *reinterpret_cast<const float4*>(&pT[rowp + 8 * s + 4]);
            step(sst[0], sst[1], pb0.x);
            step(sst[1], sst[0], pb0.y);
            step(sst[0], sst[1], pb0.z);
            step(sst[1], sst[0], pb0.w);
            step(sst[0], sst[1], pb1.x);
            step(sst[1], sst[0], pb1.y);
            step(sst[0], sst[1], pb1.z);
            step(sst[1], sst[0], pb1.w);
        }
    }

    if (q == 0)
        out[r * H_N + 16 * wv + l] = y;
}

extern "C" void kernel_launch(void* const* d_in, const int* in_sizes, int n_in,
                              void* d_out, int out_size, void* d_ws, size_t ws_size,
                              hipStream_t stream) {
    const float* x    = (const float*)d_in[0];  // [B][T][D] fp32
    const float* w    = (const float*)d_in[1];  // [D][H]    fp32
    const float* wst  = (const float*)d_in[2];  // [H][H]    fp32
    const float* bias = (const float*)d_in[3];  // [H]       fp32
    float* out = (float*)d_out;                 // [B][H]    fp32

    k_fused<<<256, 512, 0, stream>>>(x, w, wst, bias, out);
}